// Round 5
// baseline (437.003 us; speedup 1.0000x reference)
//
#include <hip/hip_runtime.h>

#define D 128
#define LN_EPS 1e-12f

typedef unsigned int uint;
typedef unsigned short ushort_t;
typedef __attribute__((ext_vector_type(8))) short bf16x8;   // 8 bf16 = 4 VGPR
typedef __attribute__((ext_vector_type(4))) float f32x4;    // MFMA 16x16 acc

__device__ inline ushort_t f2bf(float f) {  // RNE fp32 -> bf16
  uint u = __float_as_uint(f);
  u += 0x7fffu + ((u >> 16) & 1u);
  return (ushort_t)(u >> 16);
}
__device__ inline float bf2f(ushort_t h) {
  return __uint_as_float((uint)h << 16);
}
__device__ inline uint pack_bf16(float a, float b) {
  return (uint)f2bf(a) | ((uint)f2bf(b) << 16);
}

// ---------------------------------------------------------------------------
// front_kernel: three independent jobs in one launch (block-uniform branch):
//   blocks [0, embB)             : fused 4-table embedding gather + LayerNorm
//   blocks [embB, embB+histB)    : dst histogram (CSR step 1)
//   blocks [embB+histB, +256)    : weight split into hi/lo bf16, Wb[col][k]
// ---------------------------------------------------------------------------
__global__ __launch_bounds__(256) void front_kernel(
    const int* __restrict__ x,
    const float* __restrict__ syn, const float* __restrict__ lem,
    const float* __restrict__ pos, const float* __restrict__ sen,
    const float* __restrict__ g, const float* __restrict__ b,
    ushort_t* __restrict__ hH, ushort_t* __restrict__ hL, int n,
    const int* __restrict__ dst, int* __restrict__ counts, int nEdges,
    const float* __restrict__ Wl0, const float* __restrict__ Wr0,
    const float* __restrict__ Wl1, const float* __restrict__ Wr1,
    ushort_t* __restrict__ Wb0H, ushort_t* __restrict__ Wb0L,
    ushort_t* __restrict__ Wb1H, ushort_t* __restrict__ Wb1L,
    int embB, int histB) {
  int blk = blockIdx.x;
  if (blk >= embB + histB) {
    // ---- wprep
    int idx = (blk - embB - histB) * 256 + threadIdx.x;  // 0..65535
    int layer = idx >> 15;
    int e = idx & 32767;
    int col = e >> 8, k = e & 255;
    const float* Wl = layer ? Wl1 : Wl0;
    const float* Wr = layer ? Wr1 : Wr0;
    float v = (k < 128) ? Wl[col * 128 + k] : Wr[col * 128 + (k - 128)];
    ushort_t h = f2bf(v);
    float lo = v - bf2f(h);
    if (layer) {
      Wb1H[e] = h; Wb1L[e] = f2bf(lo);
    } else {
      Wb0H[e] = h; Wb0L[e] = f2bf(lo);
    }
    return;
  }
  if (blk >= embB) {
    // ---- hist
    int e = (blk - embB) * 256 + threadIdx.x;
    if (e < nEdges) atomicAdd(&counts[dst[e]], 1);
    return;
  }
  // ---- embed + LayerNorm (2 nodes per wave)
  int lane = threadIdx.x & 63;
  int q = lane & 31, s = lane >> 5;
  int node = blk * 8 + (threadIdx.x >> 6) * 2 + s;
  if (node >= n) return;
  int4 xi = ((const int4*)x)[node];  // columns [syn, pos, sen, lem]
  float4 v0 = ((const float4*)(syn + (size_t)xi.x * D))[q];
  float4 v1 = ((const float4*)(pos + (size_t)xi.y * D))[q];
  float4 v2 = ((const float4*)(sen + (size_t)xi.z * D))[q];
  float4 v3 = ((const float4*)(lem + (size_t)xi.w * D))[q];
  float4 hs;
  hs.x = v0.x + v1.x + v2.x + v3.x;
  hs.y = v0.y + v1.y + v2.y + v3.y;
  hs.z = v0.z + v1.z + v2.z + v3.z;
  hs.w = v0.w + v1.w + v2.w + v3.w;
  float sum = hs.x + hs.y + hs.z + hs.w;
#pragma unroll
  for (int off = 16; off; off >>= 1) sum += __shfl_xor(sum, off);
  float mu = sum * (1.0f / 128.0f);
  float4 d;
  d.x = hs.x - mu; d.y = hs.y - mu; d.z = hs.z - mu; d.w = hs.w - mu;
  float sq = d.x * d.x + d.y * d.y + d.z * d.z + d.w * d.w;
#pragma unroll
  for (int off = 16; off; off >>= 1) sq += __shfl_xor(sq, off);
  float rstd = rsqrtf(sq * (1.0f / 128.0f) + LN_EPS);
  float4 gg = ((const float4*)g)[q];
  float4 bb = ((const float4*)b)[q];
  float4 o;
  o.x = d.x * rstd * gg.x + bb.x;
  o.y = d.y * rstd * gg.y + bb.y;
  o.z = d.z * rstd * gg.z + bb.z;
  o.w = d.w * rstd * gg.w + bb.w;
  ushort_t hx = f2bf(o.x), hy = f2bf(o.y), hz = f2bf(o.z), hw = f2bf(o.w);
  uint2 ph;
  ph.x = (uint)hx | ((uint)hy << 16);
  ph.y = (uint)hz | ((uint)hw << 16);
  ((uint2*)(hH + (size_t)node * D))[q] = ph;
  uint2 pl;
  pl.x = pack_bf16(o.x - bf2f(hx), o.y - bf2f(hy));
  pl.y = pack_bf16(o.z - bf2f(hz), o.w - bf2f(hw));
  ((uint2*)(hL + (size_t)node * D))[q] = pl;
}

// ---------------------------------------------------------------------------
// Decoupled 2-kernel block scan (counts zero-padded to 1024 multiple).
// ---------------------------------------------------------------------------
__global__ __launch_bounds__(256) void scan_part_kernel(
    const int* __restrict__ counts, int* __restrict__ partials) {
  int t = threadIdx.x;
  int base = blockIdx.x * 1024 + t * 4;
  int4 v = *(const int4*)(counts + base);
  int s = v.x + v.y + v.z + v.w;
#pragma unroll
  for (int off = 1; off < 64; off <<= 1) s += __shfl_xor(s, off);
  __shared__ int ws[4];
  if ((t & 63) == 0) ws[t >> 6] = s;
  __syncthreads();
  if (t == 0) partials[blockIdx.x] = ws[0] + ws[1] + ws[2] + ws[3];
}

__global__ __launch_bounds__(256) void scan_write_kernel(
    const int* __restrict__ counts, const int* __restrict__ partials,
    int* __restrict__ row_ptr, int n, int E) {
  int t = threadIdx.x;
  int b = blockIdx.x;
  int off = 0;
  for (int i = 0; i < b; ++i) off += partials[i];
  int base = b * 1024 + t * 4;
  int4 v = *(const int4*)(counts + base);
  int s = v.x + v.y + v.z + v.w;
  int lane = t & 63;
  int incl = s;
#pragma unroll
  for (int dd = 1; dd < 64; dd <<= 1) {
    int u = __shfl_up(incl, dd);
    if (lane >= dd) incl += u;
  }
  __shared__ int wsum[4];
  if (lane == 63) wsum[t >> 6] = incl;
  __syncthreads();
  int wid = t >> 6;
  int wpre = 0;
#pragma unroll
  for (int w = 0; w < 4; ++w)
    if (w < wid) wpre += wsum[w];
  int excl = off + wpre + incl - s;
  int4 r;
  r.x = excl;
  r.y = excl + v.x;
  r.z = r.y + v.y;
  r.w = r.z + v.z;
  if (base + 3 < n) {
    *(int4*)(row_ptr + base) = r;
  } else {
    if (base < n) row_ptr[base] = r.x;
    if (base + 1 < n) row_ptr[base + 1] = r.y;
    if (base + 2 < n) row_ptr[base + 2] = r.z;
    if (base + 3 < n) row_ptr[base + 3] = r.w;
  }
  if (b == 0 && t == 0) row_ptr[n] = E;
}

__global__ __launch_bounds__(256) void fill_kernel(const int* __restrict__ src,
                                                   const int* __restrict__ dst,
                                                   const int* __restrict__ row_ptr,
                                                   int* __restrict__ cursor,
                                                   int* __restrict__ adj,
                                                   int nEdges) {
  int e = blockIdx.x * 256 + threadIdx.x;
  if (e >= nEdges) return;
  int d = dst[e];
  int p = atomicAdd(&cursor[d], 1);
  adj[row_ptr[d] + p] = src[e];
}

// ---------------------------------------------------------------------------
// bf16 gather mean-aggregation.  One wave per node; 16 lanes (q) cover the
// 256 B row, 4 streams (s) walk neighbors.  16-edge unroll: 4 row-loads in
// flight per lane (was 2) to double MLP on the LLC-latency-bound random
// gather.  fp32 accumulate, hi/lo bf16 split output.
// ---------------------------------------------------------------------------
__global__ __launch_bounds__(256) void gather_bf16_kernel(
    const int* __restrict__ row_ptr, const int* __restrict__ adj,
    const ushort_t* __restrict__ hb,
    ushort_t* __restrict__ aggH, ushort_t* __restrict__ aggL, int n) {
  int node = blockIdx.x * 4 + (threadIdx.x >> 6);
  if (node >= n) return;
  int lane = threadIdx.x & 63;
  int q = lane & 15, s = lane >> 4;
  int beg = row_ptr[node], end = row_ptr[node + 1];
  int count = end - beg;
  float a0 = 0.f, a1 = 0.f, a2 = 0.f, a3 = 0.f;
  float a4 = 0.f, a5 = 0.f, a6 = 0.f, a7 = 0.f;
  int lim = beg + (count & ~15);
  for (int bb = beg; bb < lim; bb += 16) {
    int e0 = adj[bb + s];
    int e1 = adj[bb + 4 + s];
    int e2 = adj[bb + 8 + s];
    int e3 = adj[bb + 12 + s];
    uint4 v0 = ((const uint4*)(hb + (size_t)e0 * D))[q];
    uint4 v1 = ((const uint4*)(hb + (size_t)e1 * D))[q];
    uint4 v2 = ((const uint4*)(hb + (size_t)e2 * D))[q];
    uint4 v3 = ((const uint4*)(hb + (size_t)e3 * D))[q];
    a0 += __uint_as_float(v0.x << 16) + __uint_as_float(v1.x << 16) +
          __uint_as_float(v2.x << 16) + __uint_as_float(v3.x << 16);
    a1 += __uint_as_float(v0.x & 0xffff0000u) + __uint_as_float(v1.x & 0xffff0000u) +
          __uint_as_float(v2.x & 0xffff0000u) + __uint_as_float(v3.x & 0xffff0000u);
    a2 += __uint_as_float(v0.y << 16) + __uint_as_float(v1.y << 16) +
          __uint_as_float(v2.y << 16) + __uint_as_float(v3.y << 16);
    a3 += __uint_as_float(v0.y & 0xffff0000u) + __uint_as_float(v1.y & 0xffff0000u) +
          __uint_as_float(v2.y & 0xffff0000u) + __uint_as_float(v3.y & 0xffff0000u);
    a4 += __uint_as_float(v0.z << 16) + __uint_as_float(v1.z << 16) +
          __uint_as_float(v2.z << 16) + __uint_as_float(v3.z << 16);
    a5 += __uint_as_float(v0.z & 0xffff0000u) + __uint_as_float(v1.z & 0xffff0000u) +
          __uint_as_float(v2.z & 0xffff0000u) + __uint_as_float(v3.z & 0xffff0000u);
    a6 += __uint_as_float(v0.w << 16) + __uint_as_float(v1.w << 16) +
          __uint_as_float(v2.w << 16) + __uint_as_float(v3.w << 16);
    a7 += __uint_as_float(v0.w & 0xffff0000u) + __uint_as_float(v1.w & 0xffff0000u) +
          __uint_as_float(v2.w & 0xffff0000u) + __uint_as_float(v3.w & 0xffff0000u);
  }
  for (int i = lim + s; i < end; i += 4) {
    int e0 = adj[i];
    uint4 v0 = ((const uint4*)(hb + (size_t)e0 * D))[q];
    a0 += __uint_as_float(v0.x << 16);
    a1 += __uint_as_float(v0.x & 0xffff0000u);
    a2 += __uint_as_float(v0.y << 16);
    a3 += __uint_as_float(v0.y & 0xffff0000u);
    a4 += __uint_as_float(v0.z << 16);
    a5 += __uint_as_float(v0.z & 0xffff0000u);
    a6 += __uint_as_float(v0.w << 16);
    a7 += __uint_as_float(v0.w & 0xffff0000u);
  }
#pragma unroll
  for (int off = 16; off <= 32; off <<= 1) {
    a0 += __shfl_xor(a0, off); a1 += __shfl_xor(a1, off);
    a2 += __shfl_xor(a2, off); a3 += __shfl_xor(a3, off);
    a4 += __shfl_xor(a4, off); a5 += __shfl_xor(a5, off);
    a6 += __shfl_xor(a6, off); a7 += __shfl_xor(a7, off);
  }
  if (s == 0) {
    float inv = 1.0f / fmaxf((float)count, 1.0f);
    float v0 = a0 * inv, v1 = a1 * inv, v2 = a2 * inv, v3 = a3 * inv;
    float v4 = a4 * inv, v5 = a5 * inv, v6 = a6 * inv, v7 = a7 * inv;
    ushort_t h0 = f2bf(v0), h1 = f2bf(v1), h2 = f2bf(v2), h3 = f2bf(v3);
    ushort_t h4 = f2bf(v4), h5 = f2bf(v5), h6 = f2bf(v6), h7 = f2bf(v7);
    uint4 ph;
    ph.x = (uint)h0 | ((uint)h1 << 16);
    ph.y = (uint)h2 | ((uint)h3 << 16);
    ph.z = (uint)h4 | ((uint)h5 << 16);
    ph.w = (uint)h6 | ((uint)h7 << 16);
    uint4 pl;
    pl.x = pack_bf16(v0 - bf2f(h0), v1 - bf2f(h1));
    pl.y = pack_bf16(v2 - bf2f(h2), v3 - bf2f(h3));
    pl.z = pack_bf16(v4 - bf2f(h4), v5 - bf2f(h5));
    pl.w = pack_bf16(v6 - bf2f(h6), v7 - bf2f(h7));
    *(uint4*)(aggH + (size_t)node * D + q * 8) = ph;
    *(uint4*)(aggL + (size_t)node * D + q * 8) = pl;
  }
}

// ---------------------------------------------------------------------------
// SAGE layer as split-bf16 MFMA GEMM, 128x128 tile.
//   out[i][j] = bias[j] + sum_k A[i][k]*B[k][j],  A=[agg|hin] (M x 256),
//   B[k][j] = Wb[j][k] (pre-split hi/lo).  hh+hl+lh (3 MFMAs) = fp32-grade.
// 4 waves in 2x2, each owns 64 rows x 64 cols (4x4 frags of
// mfma_f32_16x16x32_bf16).  A staged in LDS (4 chunks of 64 k, XOR swizzle
// byte ^= (row&7)<<4 for conflict-free ds_read_b128).  B-fragments load
// DIRECTLY from global: Wb is 128 KB, L2-resident, reused by all blocks —
// no LDS round trip (LDS 64->32 KB, half the staging per chunk).
// A/B k-slot map: k = kc*64 + ks*32 + (lane>>4)*8 + j (consistent A<->B).
// C/D: col = lane&15, row = (lane>>4)*4 + reg.
// NOTE: outH/outL may alias hinH/hinL (row-disjoint across blocks; within a
// block all hin reads complete before the epilogue) -> no __restrict__ there.
// ---------------------------------------------------------------------------
__global__ __launch_bounds__(256) void sage_mfma_kernel(
    const ushort_t* __restrict__ aggH, const ushort_t* __restrict__ aggL,
    const ushort_t* hinH, const ushort_t* hinL,
    const ushort_t* __restrict__ WbH, const ushort_t* __restrict__ WbL,
    const float* __restrict__ bias,
    float* outF, ushort_t* outH, ushort_t* outL, int n, int doRelu) {
  __shared__ ushort_t AsH[128 * 64];  // [row][k] bf16, swizzled
  __shared__ ushort_t AsL[128 * 64];
  int tid = threadIdx.x;
  int lane = tid & 63;
  int wave = tid >> 6;
  int base = blockIdx.x * 128;
  int wr = (wave & 1) * 64;   // wave row offset within tile
  int wc = (wave >> 1) * 64;  // wave col offset

  f32x4 zero = {0.f, 0.f, 0.f, 0.f};
  f32x4 acc[4][4];
#pragma unroll
  for (int i = 0; i < 4; ++i)
#pragma unroll
    for (int j = 0; j < 4; ++j) acc[i][j] = zero;

  // ---- A staging geometry: 128 rows x 64 k per chunk, 2 threads/row,
  // each thread 32 elems (64 B) per buffer.
  int row = tid >> 1;
  int half = tid & 1;
  int kb0 = half * 64;                // byte offset of this thread's 64 B
  int swz = (row & 7) << 4;
  char* aHdst = (char*)AsH + row * 128;
  char* aLdst = (char*)AsL + row * 128;
  int anode = base + row;
  if (anode >= n) anode = n - 1;

  // B fragment base: col = wc + cf*16 + (lane&15), elem k = kc*64 + ks*32
  // + (lane>>4)*8; 16 B contiguous per fragment, always L2-hot.
  int bcol0 = wc + (lane & 15);
  int bke = (lane >> 4) * 8;

  for (int kc = 0; kc < 4; ++kc) {
    // ---- stage A chunk: 128 rows x 64 k (hi+lo)
    {
      const ushort_t* sH = (kc < 2 ? aggH : hinH) +
                           (size_t)anode * D + (kc & 1) * 64 + half * 32;
      const ushort_t* sL = (kc < 2 ? aggL : hinL) +
                           (size_t)anode * D + (kc & 1) * 64 + half * 32;
      uint4 h0 = *(const uint4*)sH;
      uint4 h1 = *(const uint4*)(sH + 8);
      uint4 h2 = *(const uint4*)(sH + 16);
      uint4 h3 = *(const uint4*)(sH + 24);
      uint4 l0 = *(const uint4*)sL;
      uint4 l1 = *(const uint4*)(sL + 8);
      uint4 l2 = *(const uint4*)(sL + 16);
      uint4 l3 = *(const uint4*)(sL + 24);
      *(uint4*)(aHdst + ((kb0) ^ swz)) = h0;
      *(uint4*)(aHdst + ((kb0 + 16) ^ swz)) = h1;
      *(uint4*)(aHdst + ((kb0 + 32) ^ swz)) = h2;
      *(uint4*)(aHdst + ((kb0 + 48) ^ swz)) = h3;
      *(uint4*)(aLdst + ((kb0) ^ swz)) = l0;
      *(uint4*)(aLdst + ((kb0 + 16) ^ swz)) = l1;
      *(uint4*)(aLdst + ((kb0 + 32) ^ swz)) = l2;
      *(uint4*)(aLdst + ((kb0 + 48) ^ swz)) = l3;
    }
    __syncthreads();
    // ---- 2 K-steps of 32 per chunk
#pragma unroll
    for (int ks = 0; ks < 2; ++ks) {
      int kb = ks * 64 + (lane >> 4) * 16;  // byte offset of this lane's 8 k
      bf16x8 aHf[4], aLf[4], bHf[4], bLf[4];
#pragma unroll
      for (int rf = 0; rf < 4; ++rf) {
        int r = wr + rf * 16 + (lane & 15);
        int off = r * 128 + (kb ^ ((r & 7) << 4));
        aHf[rf] = *(const bf16x8*)((const char*)AsH + off);
        aLf[rf] = *(const bf16x8*)((const char*)AsL + off);
      }
      int ke = kc * 64 + ks * 32 + bke;  // global elem offset of 8-k slice
#pragma unroll
      for (int cf = 0; cf < 4; ++cf) {
        size_t boff = (size_t)(bcol0 + cf * 16) * 256 + ke;
        bHf[cf] = *(const bf16x8*)(WbH + boff);
        bLf[cf] = *(const bf16x8*)(WbL + boff);
      }
#pragma unroll
      for (int rf = 0; rf < 4; ++rf)
#pragma unroll
        for (int cf = 0; cf < 4; ++cf) {
          acc[rf][cf] = __builtin_amdgcn_mfma_f32_16x16x32_bf16(
              aHf[rf], bHf[cf], acc[rf][cf], 0, 0, 0);
          acc[rf][cf] = __builtin_amdgcn_mfma_f32_16x16x32_bf16(
              aHf[rf], bLf[cf], acc[rf][cf], 0, 0, 0);
          acc[rf][cf] = __builtin_amdgcn_mfma_f32_16x16x32_bf16(
              aLf[rf], bHf[cf], acc[rf][cf], 0, 0, 0);
        }
    }
    __syncthreads();
  }

  // ---- epilogue: bias, relu, fp32 and/or hi+lo bf16 stores
#pragma unroll
  for (int cf = 0; cf < 4; ++cf) {
    int j = wc + cf * 16 + (lane & 15);
    float bj = bias[j];
#pragma unroll
    for (int rf = 0; rf < 4; ++rf) {
      int r0 = base + wr + rf * 16 + (lane >> 4) * 4;
#pragma unroll
      for (int reg = 0; reg < 4; ++reg) {
        int node = r0 + reg;
        if (node >= n) continue;
        float v = acc[rf][cf][reg] + bj;
        if (doRelu) v = fmaxf(v, 0.f);
        if (outF) outF[(size_t)node * D + j] = v;
        if (outH) {
          ushort_t h = f2bf(v);
          outH[(size_t)node * D + j] = h;
          outL[(size_t)node * D + j] = f2bf(v - bf2f(h));
        }
      }
    }
  }
}

// ---------------------------------------------------------------------------
extern "C" void kernel_launch(void* const* d_in, const int* in_sizes, int n_in,
                              void* d_out, int out_size, void* d_ws,
                              size_t ws_size, hipStream_t stream) {
  const int* x = (const int*)d_in[0];
  const int* edge = (const int*)d_in[1];
  const float* syn = (const float*)d_in[2];
  const float* lem = (const float*)d_in[3];
  const float* pos = (const float*)d_in[4];
  const float* sen = (const float*)d_in[5];
  const float* ln_g = (const float*)d_in[6];
  const float* ln_b = (const float*)d_in[7];
  const float* Wl0 = (const float*)d_in[8];
  const float* bl0 = (const float*)d_in[9];
  const float* Wr0 = (const float*)d_in[10];
  const float* Wl1 = (const float*)d_in[11];
  const float* bl1 = (const float*)d_in[12];
  const float* Wr1 = (const float*)d_in[13];

  int n = in_sizes[0] / 4;
  int E = in_sizes[1] / 2;
  const int* srcI = edge;
  const int* dstI = edge + E;
  float* outp = (float*)d_out;

  size_t rowElems = (size_t)n * D;
  int nPad = (n + 1023) & ~1023;        // counts padded (zeroed) for int4 scan
  int scanBlocks = nPad >> 10;          // 1024 elems per scan block
  int rpElems = (n + 4) & ~3;           // keep counts 16B-aligned after row_ptr
  // Workspace layout:
  //   h0H | h0L | aggH | aggL   (n*128 ushort each)
  //   Wb0H | Wb0L | Wb1H | Wb1L (32768 ushort each)
  //   row_ptr[rpElems] | counts[nPad] | cursor[n] | partials[scanBlocks] | adj[E]
  ushort_t* h0H = (ushort_t*)d_ws;
  ushort_t* h0L = h0H + rowElems;
  ushort_t* aggH = h0L + rowElems;
  ushort_t* aggL = aggH + rowElems;
  ushort_t* Wb0H = aggL + rowElems;
  ushort_t* Wb0L = Wb0H + 32768;
  ushort_t* Wb1H = Wb0L + 32768;
  ushort_t* Wb1L = Wb1H + 32768;
  int* row_ptr = (int*)(Wb1L + 32768);
  int* counts = row_ptr + rpElems;
  int* cursor = counts + nPad;
  int* partials = cursor + n;
  int* adj = partials + scanBlocks;

  // zero counts (incl. pad) + cursor
  hipMemsetAsync(counts, 0, ((size_t)nPad + n) * sizeof(int), stream);

  int embB = (n + 7) / 8;
  int histB = (E + 255) / 256;
  front_kernel<<<embB + histB + 256, 256, 0, stream>>>(
      x, syn, lem, pos, sen, ln_g, ln_b, h0H, h0L, n,
      dstI, counts, E,
      Wl0, Wr0, Wl1, Wr1, Wb0H, Wb0L, Wb1H, Wb1L,
      embB, histB);

  scan_part_kernel<<<scanBlocks, 256, 0, stream>>>(counts, partials);
  scan_write_kernel<<<scanBlocks, 256, 0, stream>>>(counts, partials, row_ptr,
                                                    n, E);
  fill_kernel<<<histB, 256, 0, stream>>>(srcI, dstI, row_ptr, cursor, adj, E);

  int gBlocks = (n + 3) / 4;
  int sBlocks = (n + 127) / 128;

  // Layer 1: agg(h0) -> GEMM -> relu -> hmid (written over h0H/h0L; safe:
  // blocks own disjoint 128-row slices and read hin before the epilogue).
  gather_bf16_kernel<<<gBlocks, 256, 0, stream>>>(row_ptr, adj, h0H, aggH,
                                                  aggL, n);
  sage_mfma_kernel<<<sBlocks, 256, 0, stream>>>(aggH, aggL, h0H, h0L, Wb0H,
                                                Wb0L, bl0, nullptr, h0H, h0L,
                                                n, 1);
  // Layer 2: agg(hmid) -> GEMM -> fp32 out
  gather_bf16_kernel<<<gBlocks, 256, 0, stream>>>(row_ptr, adj, h0H, aggH,
                                                  aggL, n);
  sage_mfma_kernel<<<sBlocks, 256, 0, stream>>>(aggH, aggL, h0H, h0L, Wb1H,
                                                Wb1L, bl1, outp, nullptr,
                                                nullptr, n, 0);
}

// Round 6
// 421.901 us; speedup vs baseline: 1.0358x; 1.0358x over previous
//
#include <hip/hip_runtime.h>

#define D 128
#define LN_EPS 1e-12f

typedef unsigned int uint;
typedef unsigned short ushort_t;
typedef __attribute__((ext_vector_type(8))) short bf16x8;   // 8 bf16 = 4 VGPR
typedef __attribute__((ext_vector_type(4))) float f32x4;    // MFMA 16x16 acc

__device__ inline ushort_t f2bf(float f) {  // RNE fp32 -> bf16
  uint u = __float_as_uint(f);
  u += 0x7fffu + ((u >> 16) & 1u);
  return (ushort_t)(u >> 16);
}
__device__ inline float bf2f(ushort_t h) {
  return __uint_as_float((uint)h << 16);
}
__device__ inline uint pack_bf16(float a, float b) {
  return (uint)f2bf(a) | ((uint)f2bf(b) << 16);
}

// ---------------------------------------------------------------------------
// front_kernel: three independent jobs in one launch (block-uniform branch):
//   blocks [0, embB)             : fused 4-table embedding gather + LayerNorm
//   blocks [embB, embB+histB)    : dst histogram (CSR step 1)
//   blocks [embB+histB, +256)    : weight split into hi/lo bf16, Wb[col][k]
// ---------------------------------------------------------------------------
__global__ __launch_bounds__(256) void front_kernel(
    const int* __restrict__ x,
    const float* __restrict__ syn, const float* __restrict__ lem,
    const float* __restrict__ pos, const float* __restrict__ sen,
    const float* __restrict__ g, const float* __restrict__ b,
    ushort_t* __restrict__ hH, ushort_t* __restrict__ hL, int n,
    const int* __restrict__ dst, int* __restrict__ counts, int nEdges,
    const float* __restrict__ Wl0, const float* __restrict__ Wr0,
    const float* __restrict__ Wl1, const float* __restrict__ Wr1,
    ushort_t* __restrict__ Wb0H, ushort_t* __restrict__ Wb0L,
    ushort_t* __restrict__ Wb1H, ushort_t* __restrict__ Wb1L,
    int embB, int histB) {
  int blk = blockIdx.x;
  if (blk >= embB + histB) {
    // ---- wprep
    int idx = (blk - embB - histB) * 256 + threadIdx.x;  // 0..65535
    int layer = idx >> 15;
    int e = idx & 32767;
    int col = e >> 8, k = e & 255;
    const float* Wl = layer ? Wl1 : Wl0;
    const float* Wr = layer ? Wr1 : Wr0;
    float v = (k < 128) ? Wl[col * 128 + k] : Wr[col * 128 + (k - 128)];
    ushort_t h = f2bf(v);
    float lo = v - bf2f(h);
    if (layer) {
      Wb1H[e] = h; Wb1L[e] = f2bf(lo);
    } else {
      Wb0H[e] = h; Wb0L[e] = f2bf(lo);
    }
    return;
  }
  if (blk >= embB) {
    // ---- hist
    int e = (blk - embB) * 256 + threadIdx.x;
    if (e < nEdges) atomicAdd(&counts[dst[e]], 1);
    return;
  }
  // ---- embed + LayerNorm (2 nodes per wave)
  int lane = threadIdx.x & 63;
  int q = lane & 31, s = lane >> 5;
  int node = blk * 8 + (threadIdx.x >> 6) * 2 + s;
  if (node >= n) return;
  int4 xi = ((const int4*)x)[node];  // columns [syn, pos, sen, lem]
  float4 v0 = ((const float4*)(syn + (size_t)xi.x * D))[q];
  float4 v1 = ((const float4*)(pos + (size_t)xi.y * D))[q];
  float4 v2 = ((const float4*)(sen + (size_t)xi.z * D))[q];
  float4 v3 = ((const float4*)(lem + (size_t)xi.w * D))[q];
  float4 hs;
  hs.x = v0.x + v1.x + v2.x + v3.x;
  hs.y = v0.y + v1.y + v2.y + v3.y;
  hs.z = v0.z + v1.z + v2.z + v3.z;
  hs.w = v0.w + v1.w + v2.w + v3.w;
  float sum = hs.x + hs.y + hs.z + hs.w;
#pragma unroll
  for (int off = 16; off; off >>= 1) sum += __shfl_xor(sum, off);
  float mu = sum * (1.0f / 128.0f);
  float4 d;
  d.x = hs.x - mu; d.y = hs.y - mu; d.z = hs.z - mu; d.w = hs.w - mu;
  float sq = d.x * d.x + d.y * d.y + d.z * d.z + d.w * d.w;
#pragma unroll
  for (int off = 16; off; off >>= 1) sq += __shfl_xor(sq, off);
  float rstd = rsqrtf(sq * (1.0f / 128.0f) + LN_EPS);
  float4 gg = ((const float4*)g)[q];
  float4 bb = ((const float4*)b)[q];
  float4 o;
  o.x = d.x * rstd * gg.x + bb.x;
  o.y = d.y * rstd * gg.y + bb.y;
  o.z = d.z * rstd * gg.z + bb.z;
  o.w = d.w * rstd * gg.w + bb.w;
  ushort_t hx = f2bf(o.x), hy = f2bf(o.y), hz = f2bf(o.z), hw = f2bf(o.w);
  uint2 ph;
  ph.x = (uint)hx | ((uint)hy << 16);
  ph.y = (uint)hz | ((uint)hw << 16);
  ((uint2*)(hH + (size_t)node * D))[q] = ph;
  uint2 pl;
  pl.x = pack_bf16(o.x - bf2f(hx), o.y - bf2f(hy));
  pl.y = pack_bf16(o.z - bf2f(hz), o.w - bf2f(hw));
  ((uint2*)(hL + (size_t)node * D))[q] = pl;
}

// ---------------------------------------------------------------------------
// Decoupled 2-kernel block scan (counts zero-padded to 1024 multiple).
// ---------------------------------------------------------------------------
__global__ __launch_bounds__(256) void scan_part_kernel(
    const int* __restrict__ counts, int* __restrict__ partials) {
  int t = threadIdx.x;
  int base = blockIdx.x * 1024 + t * 4;
  int4 v = *(const int4*)(counts + base);
  int s = v.x + v.y + v.z + v.w;
#pragma unroll
  for (int off = 1; off < 64; off <<= 1) s += __shfl_xor(s, off);
  __shared__ int ws[4];
  if ((t & 63) == 0) ws[t >> 6] = s;
  __syncthreads();
  if (t == 0) partials[blockIdx.x] = ws[0] + ws[1] + ws[2] + ws[3];
}

__global__ __launch_bounds__(256) void scan_write_kernel(
    const int* __restrict__ counts, const int* __restrict__ partials,
    int* __restrict__ row_ptr, int n, int E) {
  int t = threadIdx.x;
  int b = blockIdx.x;
  int off = 0;
  for (int i = 0; i < b; ++i) off += partials[i];
  int base = b * 1024 + t * 4;
  int4 v = *(const int4*)(counts + base);
  int s = v.x + v.y + v.z + v.w;
  int lane = t & 63;
  int incl = s;
#pragma unroll
  for (int dd = 1; dd < 64; dd <<= 1) {
    int u = __shfl_up(incl, dd);
    if (lane >= dd) incl += u;
  }
  __shared__ int wsum[4];
  if (lane == 63) wsum[t >> 6] = incl;
  __syncthreads();
  int wid = t >> 6;
  int wpre = 0;
#pragma unroll
  for (int w = 0; w < 4; ++w)
    if (w < wid) wpre += wsum[w];
  int excl = off + wpre + incl - s;
  int4 r;
  r.x = excl;
  r.y = excl + v.x;
  r.z = r.y + v.y;
  r.w = r.z + v.z;
  if (base + 3 < n) {
    *(int4*)(row_ptr + base) = r;
  } else {
    if (base < n) row_ptr[base] = r.x;
    if (base + 1 < n) row_ptr[base + 1] = r.y;
    if (base + 2 < n) row_ptr[base + 2] = r.z;
    if (base + 3 < n) row_ptr[base + 3] = r.w;
  }
  if (b == 0 && t == 0) row_ptr[n] = E;
}

__global__ __launch_bounds__(256) void fill_kernel(const int* __restrict__ src,
                                                   const int* __restrict__ dst,
                                                   const int* __restrict__ row_ptr,
                                                   int* __restrict__ cursor,
                                                   int* __restrict__ adj,
                                                   int nEdges) {
  int e = blockIdx.x * 256 + threadIdx.x;
  if (e >= nEdges) return;
  int d = dst[e];
  int p = atomicAdd(&cursor[d], 1);
  adj[row_ptr[d] + p] = src[e];
}

// ---------------------------------------------------------------------------
// bf16 gather mean-aggregation.  One wave per node; 16 lanes (q) cover the
// 256 B row, 4 streams (s) walk neighbors.  Tiered unroll for max loads in
// flight at every count class: 16-edge blocks (4 loads/lane in flight),
// one optional 8-edge block (2 in flight), then <=7 tail (1 in flight).
// fp32 accumulate, hi/lo bf16 split output.
// ---------------------------------------------------------------------------
__global__ __launch_bounds__(256) void gather_bf16_kernel(
    const int* __restrict__ row_ptr, const int* __restrict__ adj,
    const ushort_t* __restrict__ hb,
    ushort_t* __restrict__ aggH, ushort_t* __restrict__ aggL, int n) {
  int node = blockIdx.x * 4 + (threadIdx.x >> 6);
  if (node >= n) return;
  int lane = threadIdx.x & 63;
  int q = lane & 15, s = lane >> 4;
  int beg = row_ptr[node], end = row_ptr[node + 1];
  int count = end - beg;
  float a0 = 0.f, a1 = 0.f, a2 = 0.f, a3 = 0.f;
  float a4 = 0.f, a5 = 0.f, a6 = 0.f, a7 = 0.f;
  int lim16 = beg + (count & ~15);
  for (int bb = beg; bb < lim16; bb += 16) {
    int e0 = adj[bb + s];
    int e1 = adj[bb + 4 + s];
    int e2 = adj[bb + 8 + s];
    int e3 = adj[bb + 12 + s];
    uint4 v0 = ((const uint4*)(hb + (size_t)e0 * D))[q];
    uint4 v1 = ((const uint4*)(hb + (size_t)e1 * D))[q];
    uint4 v2 = ((const uint4*)(hb + (size_t)e2 * D))[q];
    uint4 v3 = ((const uint4*)(hb + (size_t)e3 * D))[q];
    a0 += __uint_as_float(v0.x << 16) + __uint_as_float(v1.x << 16) +
          __uint_as_float(v2.x << 16) + __uint_as_float(v3.x << 16);
    a1 += __uint_as_float(v0.x & 0xffff0000u) + __uint_as_float(v1.x & 0xffff0000u) +
          __uint_as_float(v2.x & 0xffff0000u) + __uint_as_float(v3.x & 0xffff0000u);
    a2 += __uint_as_float(v0.y << 16) + __uint_as_float(v1.y << 16) +
          __uint_as_float(v2.y << 16) + __uint_as_float(v3.y << 16);
    a3 += __uint_as_float(v0.y & 0xffff0000u) + __uint_as_float(v1.y & 0xffff0000u) +
          __uint_as_float(v2.y & 0xffff0000u) + __uint_as_float(v3.y & 0xffff0000u);
    a4 += __uint_as_float(v0.z << 16) + __uint_as_float(v1.z << 16) +
          __uint_as_float(v2.z << 16) + __uint_as_float(v3.z << 16);
    a5 += __uint_as_float(v0.z & 0xffff0000u) + __uint_as_float(v1.z & 0xffff0000u) +
          __uint_as_float(v2.z & 0xffff0000u) + __uint_as_float(v3.z & 0xffff0000u);
    a6 += __uint_as_float(v0.w << 16) + __uint_as_float(v1.w << 16) +
          __uint_as_float(v2.w << 16) + __uint_as_float(v3.w << 16);
    a7 += __uint_as_float(v0.w & 0xffff0000u) + __uint_as_float(v1.w & 0xffff0000u) +
          __uint_as_float(v2.w & 0xffff0000u) + __uint_as_float(v3.w & 0xffff0000u);
  }
  int p = lim16;
  if (count & 8) {  // one 8-edge block, 2 loads in flight
    int e0 = adj[p + s], e1 = adj[p + 4 + s];
    uint4 v0 = ((const uint4*)(hb + (size_t)e0 * D))[q];
    uint4 v1 = ((const uint4*)(hb + (size_t)e1 * D))[q];
    a0 += __uint_as_float(v0.x << 16) + __uint_as_float(v1.x << 16);
    a1 += __uint_as_float(v0.x & 0xffff0000u) + __uint_as_float(v1.x & 0xffff0000u);
    a2 += __uint_as_float(v0.y << 16) + __uint_as_float(v1.y << 16);
    a3 += __uint_as_float(v0.y & 0xffff0000u) + __uint_as_float(v1.y & 0xffff0000u);
    a4 += __uint_as_float(v0.z << 16) + __uint_as_float(v1.z << 16);
    a5 += __uint_as_float(v0.z & 0xffff0000u) + __uint_as_float(v1.z & 0xffff0000u);
    a6 += __uint_as_float(v0.w << 16) + __uint_as_float(v1.w << 16);
    a7 += __uint_as_float(v0.w & 0xffff0000u) + __uint_as_float(v1.w & 0xffff0000u);
    p += 8;
  }
  for (int i = p + s; i < end; i += 4) {
    int e0 = adj[i];
    uint4 v0 = ((const uint4*)(hb + (size_t)e0 * D))[q];
    a0 += __uint_as_float(v0.x << 16);
    a1 += __uint_as_float(v0.x & 0xffff0000u);
    a2 += __uint_as_float(v0.y << 16);
    a3 += __uint_as_float(v0.y & 0xffff0000u);
    a4 += __uint_as_float(v0.z << 16);
    a5 += __uint_as_float(v0.z & 0xffff0000u);
    a6 += __uint_as_float(v0.w << 16);
    a7 += __uint_as_float(v0.w & 0xffff0000u);
  }
#pragma unroll
  for (int off = 16; off <= 32; off <<= 1) {
    a0 += __shfl_xor(a0, off); a1 += __shfl_xor(a1, off);
    a2 += __shfl_xor(a2, off); a3 += __shfl_xor(a3, off);
    a4 += __shfl_xor(a4, off); a5 += __shfl_xor(a5, off);
    a6 += __shfl_xor(a6, off); a7 += __shfl_xor(a7, off);
  }
  if (s == 0) {
    float inv = 1.0f / fmaxf((float)count, 1.0f);
    float v0 = a0 * inv, v1 = a1 * inv, v2 = a2 * inv, v3 = a3 * inv;
    float v4 = a4 * inv, v5 = a5 * inv, v6 = a6 * inv, v7 = a7 * inv;
    ushort_t h0 = f2bf(v0), h1 = f2bf(v1), h2 = f2bf(v2), h3 = f2bf(v3);
    ushort_t h4 = f2bf(v4), h5 = f2bf(v5), h6 = f2bf(v6), h7 = f2bf(v7);
    uint4 ph;
    ph.x = (uint)h0 | ((uint)h1 << 16);
    ph.y = (uint)h2 | ((uint)h3 << 16);
    ph.z = (uint)h4 | ((uint)h5 << 16);
    ph.w = (uint)h6 | ((uint)h7 << 16);
    uint4 pl;
    pl.x = pack_bf16(v0 - bf2f(h0), v1 - bf2f(h1));
    pl.y = pack_bf16(v2 - bf2f(h2), v3 - bf2f(h3));
    pl.z = pack_bf16(v4 - bf2f(h4), v5 - bf2f(h5));
    pl.w = pack_bf16(v6 - bf2f(h6), v7 - bf2f(h7));
    *(uint4*)(aggH + (size_t)node * D + q * 8) = ph;
    *(uint4*)(aggL + (size_t)node * D + q * 8) = pl;
  }
}

// ---------------------------------------------------------------------------
// SAGE layer as split-bf16 MFMA GEMM, 128x128 tile (round-4 version, LDS-
// staged A AND B — B-direct-from-global regressed in round 5):
//   out[i][j] = bias[j] + sum_k A[i][k]*B[k][j],  A=[agg|hin] (M x 256),
//   B[k][j] = Wb[j][k] (pre-split hi/lo).  hh+hl+lh (3 MFMAs) = fp32-grade.
// 4 waves in 2x2, each owns 64 rows x 64 cols (4x4 frags of
// mfma_f32_16x16x32_bf16).  K staged in LDS in 4 chunks of 64,
// XOR-swizzled (byte ^= (row&7)<<4) for conflict-free ds_read_b128 (G4).
// A/B k-slot map: k = (lane>>4)*8+j (consistent A<->B).
// C/D: col = lane&15, row = (lane>>4)*4 + reg.  LDS 64KB -> 2 blocks/CU.
// NOTE: outH/outL may alias hinH/hinL (row-disjoint across blocks; within a
// block all hin reads complete before the epilogue) -> no __restrict__ there.
// ---------------------------------------------------------------------------
__global__ __launch_bounds__(256) void sage_mfma_kernel(
    const ushort_t* __restrict__ aggH, const ushort_t* __restrict__ aggL,
    const ushort_t* hinH, const ushort_t* hinL,
    const ushort_t* __restrict__ WbH, const ushort_t* __restrict__ WbL,
    const float* __restrict__ bias,
    float* outF, ushort_t* outH, ushort_t* outL, int n, int doRelu) {
  __shared__ ushort_t AsH[128 * 64];  // [row][k] bf16, swizzled
  __shared__ ushort_t AsL[128 * 64];
  __shared__ ushort_t BsH[128 * 64];  // [col][k] bf16, swizzled
  __shared__ ushort_t BsL[128 * 64];
  int tid = threadIdx.x;
  int lane = tid & 63;
  int wave = tid >> 6;
  int base = blockIdx.x * 128;
  int wr = (wave & 1) * 64;   // wave row offset within tile
  int wc = (wave >> 1) * 64;  // wave col offset

  f32x4 zero = {0.f, 0.f, 0.f, 0.f};
  f32x4 acc[4][4];
#pragma unroll
  for (int i = 0; i < 4; ++i)
#pragma unroll
    for (int j = 0; j < 4; ++j) acc[i][j] = zero;

  // ---- staging geometry: A and B both 128 rows x 64 k per chunk,
  // 2 threads/row, each thread 32 elems (64 B) per buffer.
  int row = tid >> 1;
  int half = tid & 1;
  int kb0 = half * 64;                // byte offset of this thread's 64 B
  int swz = (row & 7) << 4;
  char* aHdst = (char*)AsH + row * 128;
  char* aLdst = (char*)AsL + row * 128;
  char* bHdst = (char*)BsH + row * 128;
  char* bLdst = (char*)BsL + row * 128;
  int anode = base + row;
  if (anode >= n) anode = n - 1;
  const ushort_t* wHsrc = WbH + (size_t)row * 256 + half * 32;
  const ushort_t* wLsrc = WbL + (size_t)row * 256 + half * 32;

  for (int kc = 0; kc < 4; ++kc) {
    // ---- stage A chunk: 128 rows x 64 k (hi+lo)
    {
      const ushort_t* sH = (kc < 2 ? aggH : hinH) +
                           (size_t)anode * D + (kc & 1) * 64 + half * 32;
      const ushort_t* sL = (kc < 2 ? aggL : hinL) +
                           (size_t)anode * D + (kc & 1) * 64 + half * 32;
      uint4 h0 = *(const uint4*)sH;
      uint4 h1 = *(const uint4*)(sH + 8);
      uint4 h2 = *(const uint4*)(sH + 16);
      uint4 h3 = *(const uint4*)(sH + 24);
      uint4 l0 = *(const uint4*)sL;
      uint4 l1 = *(const uint4*)(sL + 8);
      uint4 l2 = *(const uint4*)(sL + 16);
      uint4 l3 = *(const uint4*)(sL + 24);
      *(uint4*)(aHdst + ((kb0) ^ swz)) = h0;
      *(uint4*)(aHdst + ((kb0 + 16) ^ swz)) = h1;
      *(uint4*)(aHdst + ((kb0 + 32) ^ swz)) = h2;
      *(uint4*)(aHdst + ((kb0 + 48) ^ swz)) = h3;
      *(uint4*)(aLdst + ((kb0) ^ swz)) = l0;
      *(uint4*)(aLdst + ((kb0 + 16) ^ swz)) = l1;
      *(uint4*)(aLdst + ((kb0 + 32) ^ swz)) = l2;
      *(uint4*)(aLdst + ((kb0 + 48) ^ swz)) = l3;
    }
    // ---- stage B chunk: 128 cols x 64 k (hi+lo)
    {
      const ushort_t* sH = wHsrc + kc * 64;
      const ushort_t* sL = wLsrc + kc * 64;
      uint4 h0 = *(const uint4*)sH;
      uint4 h1 = *(const uint4*)(sH + 8);
      uint4 h2 = *(const uint4*)(sH + 16);
      uint4 h3 = *(const uint4*)(sH + 24);
      uint4 l0 = *(const uint4*)sL;
      uint4 l1 = *(const uint4*)(sL + 8);
      uint4 l2 = *(const uint4*)(sL + 16);
      uint4 l3 = *(const uint4*)(sL + 24);
      *(uint4*)(bHdst + ((kb0) ^ swz)) = h0;
      *(uint4*)(bHdst + ((kb0 + 16) ^ swz)) = h1;
      *(uint4*)(bHdst + ((kb0 + 32) ^ swz)) = h2;
      *(uint4*)(bHdst + ((kb0 + 48) ^ swz)) = h3;
      *(uint4*)(bLdst + ((kb0) ^ swz)) = l0;
      *(uint4*)(bLdst + ((kb0 + 16) ^ swz)) = l1;
      *(uint4*)(bLdst + ((kb0 + 32) ^ swz)) = l2;
      *(uint4*)(bLdst + ((kb0 + 48) ^ swz)) = l3;
    }
    __syncthreads();
    // ---- 2 K-steps of 32 per chunk
#pragma unroll
    for (int ks = 0; ks < 2; ++ks) {
      int kb = ks * 64 + (lane >> 4) * 16;  // byte offset of this lane's 8 k
      bf16x8 aHf[4], aLf[4], bHf[4], bLf[4];
#pragma unroll
      for (int rf = 0; rf < 4; ++rf) {
        int r = wr + rf * 16 + (lane & 15);
        int off = r * 128 + (kb ^ ((r & 7) << 4));
        aHf[rf] = *(const bf16x8*)((const char*)AsH + off);
        aLf[rf] = *(const bf16x8*)((const char*)AsL + off);
      }
#pragma unroll
      for (int cf = 0; cf < 4; ++cf) {
        int c = wc + cf * 16 + (lane & 15);
        int off = c * 128 + (kb ^ ((c & 7) << 4));
        bHf[cf] = *(const bf16x8*)((const char*)BsH + off);
        bLf[cf] = *(const bf16x8*)((const char*)BsL + off);
      }
#pragma unroll
      for (int rf = 0; rf < 4; ++rf)
#pragma unroll
        for (int cf = 0; cf < 4; ++cf) {
          acc[rf][cf] = __builtin_amdgcn_mfma_f32_16x16x32_bf16(
              aHf[rf], bHf[cf], acc[rf][cf], 0, 0, 0);
          acc[rf][cf] = __builtin_amdgcn_mfma_f32_16x16x32_bf16(
              aHf[rf], bLf[cf], acc[rf][cf], 0, 0, 0);
          acc[rf][cf] = __builtin_amdgcn_mfma_f32_16x16x32_bf16(
              aLf[rf], bHf[cf], acc[rf][cf], 0, 0, 0);
        }
    }
    __syncthreads();
  }

  // ---- epilogue: bias, relu, fp32 and/or hi+lo bf16 stores
#pragma unroll
  for (int cf = 0; cf < 4; ++cf) {
    int j = wc + cf * 16 + (lane & 15);
    float bj = bias[j];
#pragma unroll
    for (int rf = 0; rf < 4; ++rf) {
      int r0 = base + wr + rf * 16 + (lane >> 4) * 4;
#pragma unroll
      for (int reg = 0; reg < 4; ++reg) {
        int node = r0 + reg;
        if (node >= n) continue;
        float v = acc[rf][cf][reg] + bj;
        if (doRelu) v = fmaxf(v, 0.f);
        if (outF) outF[(size_t)node * D + j] = v;
        if (outH) {
          ushort_t h = f2bf(v);
          outH[(size_t)node * D + j] = h;
          outL[(size_t)node * D + j] = f2bf(v - bf2f(h));
        }
      }
    }
  }
}

// ---------------------------------------------------------------------------
extern "C" void kernel_launch(void* const* d_in, const int* in_sizes, int n_in,
                              void* d_out, int out_size, void* d_ws,
                              size_t ws_size, hipStream_t stream) {
  const int* x = (const int*)d_in[0];
  const int* edge = (const int*)d_in[1];
  const float* syn = (const float*)d_in[2];
  const float* lem = (const float*)d_in[3];
  const float* pos = (const float*)d_in[4];
  const float* sen = (const float*)d_in[5];
  const float* ln_g = (const float*)d_in[6];
  const float* ln_b = (const float*)d_in[7];
  const float* Wl0 = (const float*)d_in[8];
  const float* bl0 = (const float*)d_in[9];
  const float* Wr0 = (const float*)d_in[10];
  const float* Wl1 = (const float*)d_in[11];
  const float* bl1 = (const float*)d_in[12];
  const float* Wr1 = (const float*)d_in[13];

  int n = in_sizes[0] / 4;
  int E = in_sizes[1] / 2;
  const int* srcI = edge;
  const int* dstI = edge + E;
  float* outp = (float*)d_out;

  size_t rowElems = (size_t)n * D;
  int nPad = (n + 1023) & ~1023;        // counts padded (zeroed) for int4 scan
  int scanBlocks = nPad >> 10;          // 1024 elems per scan block
  int rpElems = (n + 4) & ~3;           // keep counts 16B-aligned after row_ptr
  // Workspace layout:
  //   h0H | h0L | aggH | aggL   (n*128 ushort each)
  //   Wb0H | Wb0L | Wb1H | Wb1L (32768 ushort each)
  //   row_ptr[rpElems] | counts[nPad] | cursor[n] | partials[scanBlocks] | adj[E]
  ushort_t* h0H = (ushort_t*)d_ws;
  ushort_t* h0L = h0H + rowElems;
  ushort_t* aggH = h0L + rowElems;
  ushort_t* aggL = aggH + rowElems;
  ushort_t* Wb0H = aggL + rowElems;
  ushort_t* Wb0L = Wb0H + 32768;
  ushort_t* Wb1H = Wb0L + 32768;
  ushort_t* Wb1L = Wb1H + 32768;
  int* row_ptr = (int*)(Wb1L + 32768);
  int* counts = row_ptr + rpElems;
  int* cursor = counts + nPad;
  int* partials = cursor + n;
  int* adj = partials + scanBlocks;

  // zero counts (incl. pad) + cursor
  hipMemsetAsync(counts, 0, ((size_t)nPad + n) * sizeof(int), stream);

  int embB = (n + 7) / 8;
  int histB = (E + 255) / 256;
  front_kernel<<<embB + histB + 256, 256, 0, stream>>>(
      x, syn, lem, pos, sen, ln_g, ln_b, h0H, h0L, n,
      dstI, counts, E,
      Wl0, Wr0, Wl1, Wr1, Wb0H, Wb0L, Wb1H, Wb1L,
      embB, histB);

  scan_part_kernel<<<scanBlocks, 256, 0, stream>>>(counts, partials);
  scan_write_kernel<<<scanBlocks, 256, 0, stream>>>(counts, partials, row_ptr,
                                                    n, E);
  fill_kernel<<<histB, 256, 0, stream>>>(srcI, dstI, row_ptr, cursor, adj, E);

  int gBlocks = (n + 3) / 4;
  int sBlocks = (n + 127) / 128;

  // Layer 1: agg(h0) -> GEMM -> relu -> hmid (written over h0H/h0L; safe:
  // blocks own disjoint 128-row slices and read hin before the epilogue).
  gather_bf16_kernel<<<gBlocks, 256, 0, stream>>>(row_ptr, adj, h0H, aggH,
                                                  aggL, n);
  sage_mfma_kernel<<<sBlocks, 256, 0, stream>>>(aggH, aggL, h0H, h0L, Wb0H,
                                                Wb0L, bl0, nullptr, h0H, h0L,
                                                n, 1);
  // Layer 2: agg(hmid) -> GEMM -> fp32 out
  gather_bf16_kernel<<<gBlocks, 256, 0, stream>>>(row_ptr, adj, h0H, aggH,
                                                  aggL, n);
  sage_mfma_kernel<<<sBlocks, 256, 0, stream>>>(aggH, aggL, h0H, h0L, Wb1H,
                                                Wb1L, bl1, outp, nullptr,
                                                nullptr, n, 0);
}

// Round 7
// 407.721 us; speedup vs baseline: 1.0718x; 1.0348x over previous
//
#include <hip/hip_runtime.h>

#define D 128
#define LN_EPS 1e-12f

typedef unsigned int uint;
typedef unsigned short ushort_t;
typedef __attribute__((ext_vector_type(8))) short bf16x8;   // 8 bf16 = 4 VGPR
typedef __attribute__((ext_vector_type(4))) float f32x4;    // MFMA 16x16 acc

typedef const __attribute__((address_space(1))) void gvoid_t;
typedef __attribute__((address_space(3))) void lvoid_t;
__device__ __forceinline__ void gl_lds16(const void* g, void* l) {
  // 16B per lane, LDS dest = uniform base + lane*16 (linear); source is
  // per-lane, so swizzle is applied on the GLOBAL address (m173 pattern).
  __builtin_amdgcn_global_load_lds((gvoid_t*)g, (lvoid_t*)l, 16, 0, 0);
}

__device__ inline ushort_t f2bf(float f) {  // RNE fp32 -> bf16
  uint u = __float_as_uint(f);
  u += 0x7fffu + ((u >> 16) & 1u);
  return (ushort_t)(u >> 16);
}
__device__ inline float bf2f(ushort_t h) {
  return __uint_as_float((uint)h << 16);
}
__device__ inline uint pack_bf16(float a, float b) {
  return (uint)f2bf(a) | ((uint)f2bf(b) << 16);
}

// ---------------------------------------------------------------------------
// front_kernel: three independent jobs in one launch (block-uniform branch):
//   blocks [0, embB)             : fused 4-table embedding gather + LayerNorm
//   blocks [embB, embB+histB)    : dst histogram + per-edge rank (CSR step 1)
//   blocks [embB+histB, +256)    : weight split into hi/lo bf16, Wb[col][k]
// ---------------------------------------------------------------------------
__global__ __launch_bounds__(256) void front_kernel(
    const int* __restrict__ x,
    const float* __restrict__ syn, const float* __restrict__ lem,
    const float* __restrict__ pos, const float* __restrict__ sen,
    const float* __restrict__ g, const float* __restrict__ b,
    ushort_t* __restrict__ hH, ushort_t* __restrict__ hL, int n,
    const int* __restrict__ dst, int* __restrict__ counts,
    int* __restrict__ rank, int nEdges,
    const float* __restrict__ Wl0, const float* __restrict__ Wr0,
    const float* __restrict__ Wl1, const float* __restrict__ Wr1,
    ushort_t* __restrict__ Wb0H, ushort_t* __restrict__ Wb0L,
    ushort_t* __restrict__ Wb1H, ushort_t* __restrict__ Wb1L,
    int embB, int histB) {
  int blk = blockIdx.x;
  if (blk >= embB + histB) {
    // ---- wprep
    int idx = (blk - embB - histB) * 256 + threadIdx.x;  // 0..65535
    int layer = idx >> 15;
    int e = idx & 32767;
    int col = e >> 8, k = e & 255;
    const float* Wl = layer ? Wl1 : Wl0;
    const float* Wr = layer ? Wr1 : Wr0;
    float v = (k < 128) ? Wl[col * 128 + k] : Wr[col * 128 + (k - 128)];
    ushort_t h = f2bf(v);
    float lo = v - bf2f(h);
    if (layer) {
      Wb1H[e] = h; Wb1L[e] = f2bf(lo);
    } else {
      Wb0H[e] = h; Wb0L[e] = f2bf(lo);
    }
    return;
  }
  if (blk >= embB) {
    // ---- hist + rank (rank makes fill atomic-free)
    int e = (blk - embB) * 256 + threadIdx.x;
    if (e < nEdges) rank[e] = atomicAdd(&counts[dst[e]], 1);
    return;
  }
  // ---- embed + LayerNorm (2 nodes per wave)
  int lane = threadIdx.x & 63;
  int q = lane & 31, s = lane >> 5;
  int node = blk * 8 + (threadIdx.x >> 6) * 2 + s;
  if (node >= n) return;
  int4 xi = ((const int4*)x)[node];  // columns [syn, pos, sen, lem]
  float4 v0 = ((const float4*)(syn + (size_t)xi.x * D))[q];
  float4 v1 = ((const float4*)(pos + (size_t)xi.y * D))[q];
  float4 v2 = ((const float4*)(sen + (size_t)xi.z * D))[q];
  float4 v3 = ((const float4*)(lem + (size_t)xi.w * D))[q];
  float4 hs;
  hs.x = v0.x + v1.x + v2.x + v3.x;
  hs.y = v0.y + v1.y + v2.y + v3.y;
  hs.z = v0.z + v1.z + v2.z + v3.z;
  hs.w = v0.w + v1.w + v2.w + v3.w;
  float sum = hs.x + hs.y + hs.z + hs.w;
#pragma unroll
  for (int off = 16; off; off >>= 1) sum += __shfl_xor(sum, off);
  float mu = sum * (1.0f / 128.0f);
  float4 d;
  d.x = hs.x - mu; d.y = hs.y - mu; d.z = hs.z - mu; d.w = hs.w - mu;
  float sq = d.x * d.x + d.y * d.y + d.z * d.z + d.w * d.w;
#pragma unroll
  for (int off = 16; off; off >>= 1) sq += __shfl_xor(sq, off);
  float rstd = rsqrtf(sq * (1.0f / 128.0f) + LN_EPS);
  float4 gg = ((const float4*)g)[q];
  float4 bb = ((const float4*)b)[q];
  float4 o;
  o.x = d.x * rstd * gg.x + bb.x;
  o.y = d.y * rstd * gg.y + bb.y;
  o.z = d.z * rstd * gg.z + bb.z;
  o.w = d.w * rstd * gg.w + bb.w;
  ushort_t hx = f2bf(o.x), hy = f2bf(o.y), hz = f2bf(o.z), hw = f2bf(o.w);
  uint2 ph;
  ph.x = (uint)hx | ((uint)hy << 16);
  ph.y = (uint)hz | ((uint)hw << 16);
  ((uint2*)(hH + (size_t)node * D))[q] = ph;
  uint2 pl;
  pl.x = pack_bf16(o.x - bf2f(hx), o.y - bf2f(hy));
  pl.y = pack_bf16(o.z - bf2f(hz), o.w - bf2f(hw));
  ((uint2*)(hL + (size_t)node * D))[q] = pl;
}

// ---------------------------------------------------------------------------
// Decoupled 2-kernel block scan (counts zero-padded to 1024 multiple).
// ---------------------------------------------------------------------------
__global__ __launch_bounds__(256) void scan_part_kernel(
    const int* __restrict__ counts, int* __restrict__ partials) {
  int t = threadIdx.x;
  int base = blockIdx.x * 1024 + t * 4;
  int4 v = *(const int4*)(counts + base);
  int s = v.x + v.y + v.z + v.w;
#pragma unroll
  for (int off = 1; off < 64; off <<= 1) s += __shfl_xor(s, off);
  __shared__ int ws[4];
  if ((t & 63) == 0) ws[t >> 6] = s;
  __syncthreads();
  if (t == 0) partials[blockIdx.x] = ws[0] + ws[1] + ws[2] + ws[3];
}

__global__ __launch_bounds__(256) void scan_write_kernel(
    const int* __restrict__ counts, const int* __restrict__ partials,
    int* __restrict__ row_ptr, int n, int E) {
  int t = threadIdx.x;
  int b = blockIdx.x;
  int off = 0;
  for (int i = 0; i < b; ++i) off += partials[i];
  int base = b * 1024 + t * 4;
  int4 v = *(const int4*)(counts + base);
  int s = v.x + v.y + v.z + v.w;
  int lane = t & 63;
  int incl = s;
#pragma unroll
  for (int dd = 1; dd < 64; dd <<= 1) {
    int u = __shfl_up(incl, dd);
    if (lane >= dd) incl += u;
  }
  __shared__ int wsum[4];
  if (lane == 63) wsum[t >> 6] = incl;
  __syncthreads();
  int wid = t >> 6;
  int wpre = 0;
#pragma unroll
  for (int w = 0; w < 4; ++w)
    if (w < wid) wpre += wsum[w];
  int excl = off + wpre + incl - s;
  int4 r;
  r.x = excl;
  r.y = excl + v.x;
  r.z = r.y + v.y;
  r.w = r.z + v.z;
  if (base + 3 < n) {
    *(int4*)(row_ptr + base) = r;
  } else {
    if (base < n) row_ptr[base] = r.x;
    if (base + 1 < n) row_ptr[base + 1] = r.y;
    if (base + 2 < n) row_ptr[base + 2] = r.z;
    if (base + 3 < n) row_ptr[base + 3] = r.w;
  }
  if (b == 0 && t == 0) row_ptr[n] = E;
}

// atomic-free: position = row_ptr[dst] + rank (rank from hist pass)
__global__ __launch_bounds__(256) void fill_kernel(const int* __restrict__ src,
                                                   const int* __restrict__ dst,
                                                   const int* __restrict__ row_ptr,
                                                   const int* __restrict__ rank,
                                                   int* __restrict__ adj,
                                                   int nEdges) {
  int e = blockIdx.x * 256 + threadIdx.x;
  if (e >= nEdges) return;
  int d = dst[e];
  adj[row_ptr[d] + rank[e]] = src[e];
}

// ---------------------------------------------------------------------------
// bf16 gather mean-aggregation.  One wave per node; 16 lanes (q) cover the
// 256 B row, 4 streams (s) walk neighbors.  Tiered unroll: 16-edge blocks
// (4 loads/lane in flight), one 8-edge block (2), <=7 tail (1).
// fp32 accumulate, hi/lo bf16 split output.
// ---------------------------------------------------------------------------
__global__ __launch_bounds__(256) void gather_bf16_kernel(
    const int* __restrict__ row_ptr, const int* __restrict__ adj,
    const ushort_t* __restrict__ hb,
    ushort_t* __restrict__ aggH, ushort_t* __restrict__ aggL, int n) {
  int node = blockIdx.x * 4 + (threadIdx.x >> 6);
  if (node >= n) return;
  int lane = threadIdx.x & 63;
  int q = lane & 15, s = lane >> 4;
  int beg = row_ptr[node], end = row_ptr[node + 1];
  int count = end - beg;
  float a0 = 0.f, a1 = 0.f, a2 = 0.f, a3 = 0.f;
  float a4 = 0.f, a5 = 0.f, a6 = 0.f, a7 = 0.f;
  int lim16 = beg + (count & ~15);
  for (int bb = beg; bb < lim16; bb += 16) {
    int e0 = adj[bb + s];
    int e1 = adj[bb + 4 + s];
    int e2 = adj[bb + 8 + s];
    int e3 = adj[bb + 12 + s];
    uint4 v0 = ((const uint4*)(hb + (size_t)e0 * D))[q];
    uint4 v1 = ((const uint4*)(hb + (size_t)e1 * D))[q];
    uint4 v2 = ((const uint4*)(hb + (size_t)e2 * D))[q];
    uint4 v3 = ((const uint4*)(hb + (size_t)e3 * D))[q];
    a0 += __uint_as_float(v0.x << 16) + __uint_as_float(v1.x << 16) +
          __uint_as_float(v2.x << 16) + __uint_as_float(v3.x << 16);
    a1 += __uint_as_float(v0.x & 0xffff0000u) + __uint_as_float(v1.x & 0xffff0000u) +
          __uint_as_float(v2.x & 0xffff0000u) + __uint_as_float(v3.x & 0xffff0000u);
    a2 += __uint_as_float(v0.y << 16) + __uint_as_float(v1.y << 16) +
          __uint_as_float(v2.y << 16) + __uint_as_float(v3.y << 16);
    a3 += __uint_as_float(v0.y & 0xffff0000u) + __uint_as_float(v1.y & 0xffff0000u) +
          __uint_as_float(v2.y & 0xffff0000u) + __uint_as_float(v3.y & 0xffff0000u);
    a4 += __uint_as_float(v0.z << 16) + __uint_as_float(v1.z << 16) +
          __uint_as_float(v2.z << 16) + __uint_as_float(v3.z << 16);
    a5 += __uint_as_float(v0.z & 0xffff0000u) + __uint_as_float(v1.z & 0xffff0000u) +
          __uint_as_float(v2.z & 0xffff0000u) + __uint_as_float(v3.z & 0xffff0000u);
    a6 += __uint_as_float(v0.w << 16) + __uint_as_float(v1.w << 16) +
          __uint_as_float(v2.w << 16) + __uint_as_float(v3.w << 16);
    a7 += __uint_as_float(v0.w & 0xffff0000u) + __uint_as_float(v1.w & 0xffff0000u) +
          __uint_as_float(v2.w & 0xffff0000u) + __uint_as_float(v3.w & 0xffff0000u);
  }
  int p = lim16;
  if (count & 8) {  // one 8-edge block, 2 loads in flight
    int e0 = adj[p + s], e1 = adj[p + 4 + s];
    uint4 v0 = ((const uint4*)(hb + (size_t)e0 * D))[q];
    uint4 v1 = ((const uint4*)(hb + (size_t)e1 * D))[q];
    a0 += __uint_as_float(v0.x << 16) + __uint_as_float(v1.x << 16);
    a1 += __uint_as_float(v0.x & 0xffff0000u) + __uint_as_float(v1.x & 0xffff0000u);
    a2 += __uint_as_float(v0.y << 16) + __uint_as_float(v1.y << 16);
    a3 += __uint_as_float(v0.y & 0xffff0000u) + __uint_as_float(v1.y & 0xffff0000u);
    a4 += __uint_as_float(v0.z << 16) + __uint_as_float(v1.z << 16);
    a5 += __uint_as_float(v0.z & 0xffff0000u) + __uint_as_float(v1.z & 0xffff0000u);
    a6 += __uint_as_float(v0.w << 16) + __uint_as_float(v1.w << 16);
    a7 += __uint_as_float(v0.w & 0xffff0000u) + __uint_as_float(v1.w & 0xffff0000u);
    p += 8;
  }
  for (int i = p + s; i < end; i += 4) {
    int e0 = adj[i];
    uint4 v0 = ((const uint4*)(hb + (size_t)e0 * D))[q];
    a0 += __uint_as_float(v0.x << 16);
    a1 += __uint_as_float(v0.x & 0xffff0000u);
    a2 += __uint_as_float(v0.y << 16);
    a3 += __uint_as_float(v0.y & 0xffff0000u);
    a4 += __uint_as_float(v0.z << 16);
    a5 += __uint_as_float(v0.z & 0xffff0000u);
    a6 += __uint_as_float(v0.w << 16);
    a7 += __uint_as_float(v0.w & 0xffff0000u);
  }
#pragma unroll
  for (int off = 16; off <= 32; off <<= 1) {
    a0 += __shfl_xor(a0, off); a1 += __shfl_xor(a1, off);
    a2 += __shfl_xor(a2, off); a3 += __shfl_xor(a3, off);
    a4 += __shfl_xor(a4, off); a5 += __shfl_xor(a5, off);
    a6 += __shfl_xor(a6, off); a7 += __shfl_xor(a7, off);
  }
  if (s == 0) {
    float inv = 1.0f / fmaxf((float)count, 1.0f);
    float v0 = a0 * inv, v1 = a1 * inv, v2 = a2 * inv, v3 = a3 * inv;
    float v4 = a4 * inv, v5 = a5 * inv, v6 = a6 * inv, v7 = a7 * inv;
    ushort_t h0 = f2bf(v0), h1 = f2bf(v1), h2 = f2bf(v2), h3 = f2bf(v3);
    ushort_t h4 = f2bf(v4), h5 = f2bf(v5), h6 = f2bf(v6), h7 = f2bf(v7);
    uint4 ph;
    ph.x = (uint)h0 | ((uint)h1 << 16);
    ph.y = (uint)h2 | ((uint)h3 << 16);
    ph.z = (uint)h4 | ((uint)h5 << 16);
    ph.w = (uint)h6 | ((uint)h7 << 16);
    uint4 pl;
    pl.x = pack_bf16(v0 - bf2f(h0), v1 - bf2f(h1));
    pl.y = pack_bf16(v2 - bf2f(h2), v3 - bf2f(h3));
    pl.z = pack_bf16(v4 - bf2f(h4), v5 - bf2f(h5));
    pl.w = pack_bf16(v6 - bf2f(h6), v7 - bf2f(h7));
    *(uint4*)(aggH + (size_t)node * D + q * 8) = ph;
    *(uint4*)(aggL + (size_t)node * D + q * 8) = pl;
  }
}

// ---------------------------------------------------------------------------
// SAGE layer as split-bf16 MFMA GEMM, 128x128 tile.  Staging now uses
// global_load_lds width-16 (no VGPR round-trip; ladder's biggest lever):
// LDS dest is LINEAR (wave-uniform base + lane*16); the XOR swizzle
// byte ^= ((row&7)<<4) is applied to the per-lane GLOBAL source address, so
// LDS[row][c'] = global[row][c' ^ swz] — identical bytes to the old
// reg-staged path; fragment reads unchanged (read at kb ^ swz).
// 16 gl_lds16 calls per wave per chunk stage A(hi,lo)+B(hi,lo) = 64 KB.
// A/B k-slot map: k = (lane>>4)*8+j.  C/D: col = lane&15, row=(lane>>4)*4+reg.
// NOTE: outH/outL may alias hinH/hinL (row-disjoint across blocks; within a
// block all hin reads complete before the epilogue) -> no __restrict__ there.
// ---------------------------------------------------------------------------
__global__ __launch_bounds__(256) void sage_mfma_kernel(
    const ushort_t* __restrict__ aggH, const ushort_t* __restrict__ aggL,
    const ushort_t* hinH, const ushort_t* hinL,
    const ushort_t* __restrict__ WbH, const ushort_t* __restrict__ WbL,
    const float* __restrict__ bias,
    float* outF, ushort_t* outH, ushort_t* outL, int n, int doRelu) {
  __shared__ ushort_t AsH[128 * 64];  // [row][k] bf16, swizzled content
  __shared__ ushort_t AsL[128 * 64];
  __shared__ ushort_t BsH[128 * 64];  // [col][k] bf16, swizzled content
  __shared__ ushort_t BsL[128 * 64];
  int tid = threadIdx.x;
  int lane = tid & 63;
  int wave = tid >> 6;
  int base = blockIdx.x * 128;
  int wr = (wave & 1) * 64;   // wave row offset within tile
  int wc = (wave >> 1) * 64;  // wave col offset

  f32x4 zero = {0.f, 0.f, 0.f, 0.f};
  f32x4 acc[4][4];
#pragma unroll
  for (int i = 0; i < 4; ++i)
#pragma unroll
    for (int j = 0; j < 4; ++j) acc[i][j] = zero;

  for (int kc = 0; kc < 4; ++kc) {
    // ---- stage chunk via global_load_lds (4 calls x 4 buffers per wave).
    // slot = 16B unit; row = slot>>3 (128B rows), cs = swizzled byte-in-row.
    const char* aH = (const char*)((kc < 2) ? aggH : hinH);
    const char* aL = (const char*)((kc < 2) ? aggL : hinL);
    int aoff = (kc & 1) * 128;  // byte offset within 256B A row
    int boff = kc * 128;        // byte offset within 512B Wb row
#pragma unroll
    for (int i = 0; i < 4; ++i) {
      int grp = i * 4 + wave;           // 0..15, wave-uniform
      int slot = grp * 64 + lane;       // 0..1023
      int row = slot >> 3;              // 0..127
      int cs = ((slot & 7) * 16) ^ ((row & 7) << 4);
      int anode = base + row;
      if (anode >= n) anode = n - 1;
      size_t abyte = (size_t)anode * 256 + aoff + cs;
      size_t bbyte = (size_t)row * 512 + boff + cs;
      uint ldsb = (uint)grp * 1024;     // wave-uniform LDS base
      gl_lds16(aH + abyte, (char*)AsH + ldsb);
      gl_lds16(aL + abyte, (char*)AsL + ldsb);
      gl_lds16((const char*)WbH + bbyte, (char*)BsH + ldsb);
      gl_lds16((const char*)WbL + bbyte, (char*)BsL + ldsb);
    }
    __syncthreads();  // drains vmcnt (LDS-DMA) before any fragment read
    // ---- 2 K-steps of 32 per chunk (unchanged)
#pragma unroll
    for (int ks = 0; ks < 2; ++ks) {
      int kb = ks * 64 + (lane >> 4) * 16;  // byte offset of this lane's 8 k
      bf16x8 aHf[4], aLf[4], bHf[4], bLf[4];
#pragma unroll
      for (int rf = 0; rf < 4; ++rf) {
        int r = wr + rf * 16 + (lane & 15);
        int off = r * 128 + (kb ^ ((r & 7) << 4));
        aHf[rf] = *(const bf16x8*)((const char*)AsH + off);
        aLf[rf] = *(const bf16x8*)((const char*)AsL + off);
      }
#pragma unroll
      for (int cf = 0; cf < 4; ++cf) {
        int c = wc + cf * 16 + (lane & 15);
        int off = c * 128 + (kb ^ ((c & 7) << 4));
        bHf[cf] = *(const bf16x8*)((const char*)BsH + off);
        bLf[cf] = *(const bf16x8*)((const char*)BsL + off);
      }
#pragma unroll
      for (int rf = 0; rf < 4; ++rf)
#pragma unroll
        for (int cf = 0; cf < 4; ++cf) {
          acc[rf][cf] = __builtin_amdgcn_mfma_f32_16x16x32_bf16(
              aHf[rf], bHf[cf], acc[rf][cf], 0, 0, 0);
          acc[rf][cf] = __builtin_amdgcn_mfma_f32_16x16x32_bf16(
              aHf[rf], bLf[cf], acc[rf][cf], 0, 0, 0);
          acc[rf][cf] = __builtin_amdgcn_mfma_f32_16x16x32_bf16(
              aLf[rf], bHf[cf], acc[rf][cf], 0, 0, 0);
        }
    }
    __syncthreads();  // WAR: compute done before next chunk's DMA overwrites
  }

  // ---- epilogue: bias, relu, fp32 and/or hi+lo bf16 stores
#pragma unroll
  for (int cf = 0; cf < 4; ++cf) {
    int j = wc + cf * 16 + (lane & 15);
    float bj = bias[j];
#pragma unroll
    for (int rf = 0; rf < 4; ++rf) {
      int r0 = base + wr + rf * 16 + (lane >> 4) * 4;
#pragma unroll
      for (int reg = 0; reg < 4; ++reg) {
        int node = r0 + reg;
        if (node >= n) continue;
        float v = acc[rf][cf][reg] + bj;
        if (doRelu) v = fmaxf(v, 0.f);
        if (outF) outF[(size_t)node * D + j] = v;
        if (outH) {
          ushort_t h = f2bf(v);
          outH[(size_t)node * D + j] = h;
          outL[(size_t)node * D + j] = f2bf(v - bf2f(h));
        }
      }
    }
  }
}

// ---------------------------------------------------------------------------
extern "C" void kernel_launch(void* const* d_in, const int* in_sizes, int n_in,
                              void* d_out, int out_size, void* d_ws,
                              size_t ws_size, hipStream_t stream) {
  const int* x = (const int*)d_in[0];
  const int* edge = (const int*)d_in[1];
  const float* syn = (const float*)d_in[2];
  const float* lem = (const float*)d_in[3];
  const float* pos = (const float*)d_in[4];
  const float* sen = (const float*)d_in[5];
  const float* ln_g = (const float*)d_in[6];
  const float* ln_b = (const float*)d_in[7];
  const float* Wl0 = (const float*)d_in[8];
  const float* bl0 = (const float*)d_in[9];
  const float* Wr0 = (const float*)d_in[10];
  const float* Wl1 = (const float*)d_in[11];
  const float* bl1 = (const float*)d_in[12];
  const float* Wr1 = (const float*)d_in[13];

  int n = in_sizes[0] / 4;
  int E = in_sizes[1] / 2;
  const int* srcI = edge;
  const int* dstI = edge + E;
  float* outp = (float*)d_out;

  size_t rowElems = (size_t)n * D;
  int nPad = (n + 1023) & ~1023;        // counts padded (zeroed) for int4 scan
  int scanBlocks = nPad >> 10;          // 1024 elems per scan block
  int rpElems = (n + 4) & ~3;           // keep counts 16B-aligned after row_ptr
  // Workspace layout:
  //   h0H | h0L | aggH | aggL   (n*128 ushort each)
  //   Wb0H | Wb0L | Wb1H | Wb1L (32768 ushort each)
  //   row_ptr[rpElems] | counts[nPad] | rank[E] | partials[scanBlocks] | adj[E]
  ushort_t* h0H = (ushort_t*)d_ws;
  ushort_t* h0L = h0H + rowElems;
  ushort_t* aggH = h0L + rowElems;
  ushort_t* aggL = aggH + rowElems;
  ushort_t* Wb0H = aggL + rowElems;
  ushort_t* Wb0L = Wb0H + 32768;
  ushort_t* Wb1H = Wb0L + 32768;
  ushort_t* Wb1L = Wb1H + 32768;
  int* row_ptr = (int*)(Wb1L + 32768);
  int* counts = row_ptr + rpElems;
  int* rank = counts + nPad;
  int* partials = rank + E;
  int* adj = partials + scanBlocks;

  // zero counts (incl. pad); rank needs no init (fully written by hist)
  hipMemsetAsync(counts, 0, (size_t)nPad * sizeof(int), stream);

  int embB = (n + 7) / 8;
  int histB = (E + 255) / 256;
  front_kernel<<<embB + histB + 256, 256, 0, stream>>>(
      x, syn, lem, pos, sen, ln_g, ln_b, h0H, h0L, n,
      dstI, counts, rank, E,
      Wl0, Wr0, Wl1, Wr1, Wb0H, Wb0L, Wb1H, Wb1L,
      embB, histB);

  scan_part_kernel<<<scanBlocks, 256, 0, stream>>>(counts, partials);
  scan_write_kernel<<<scanBlocks, 256, 0, stream>>>(counts, partials, row_ptr,
                                                    n, E);
  fill_kernel<<<histB, 256, 0, stream>>>(srcI, dstI, row_ptr, rank, adj, E);

  int gBlocks = (n + 3) / 4;
  int sBlocks = (n + 127) / 128;

  // Layer 1: agg(h0) -> GEMM -> relu -> hmid (written over h0H/h0L; safe:
  // blocks own disjoint 128-row slices and read hin before the epilogue).
  gather_bf16_kernel<<<gBlocks, 256, 0, stream>>>(row_ptr, adj, h0H, aggH,
                                                  aggL, n);
  sage_mfma_kernel<<<sBlocks, 256, 0, stream>>>(aggH, aggL, h0H, h0L, Wb0H,
                                                Wb0L, bl0, nullptr, h0H, h0L,
                                                n, 1);
  // Layer 2: agg(hmid) -> GEMM -> fp32 out
  gather_bf16_kernel<<<gBlocks, 256, 0, stream>>>(row_ptr, adj, h0H, aggH,
                                                  aggL, n);
  sage_mfma_kernel<<<sBlocks, 256, 0, stream>>>(aggH, aggL, h0H, h0L, Wb1H,
                                                Wb1L, bl1, outp, nullptr,
                                                nullptr, n, 0);
}